// Round 4
// baseline (855.641 us; speedup 1.0000x reference)
//
#include <hip/hip_runtime.h>
#include <stdint.h>

// out[t,b,c,h,w] = (t - 64*x >= 0) * (threefry-uniform(fold_in(key(0),1)) <= 0.75)
// out shape (64,16,3,224,224) fp32; N = 154,140,672 < 2^32.
// JAX partitionable random_bits (32-bit): bits[j] = o0 ^ o1 of
// threefry2x32(rkey, (0, j))  [verified bit-exact in R3, absmax=0].
static constexpr uint32_t T = 64;
static constexpr uint32_t M = 16u * 3u * 224u * 224u;  // 2,408,448 per timestep

// uniform = bitcast((bits>>9)|0x3F800000)-1 <= 0.75  <=>  bits <= 0xC00001FF
static constexpr uint32_t BITS_LE = 0xC00001FFu;

// Host-precomputed threefry key schedule.
// Init fold: x1 = j + k1; after round-1's "x0 += x1": x0 = j + (k0+k1) = j + k01,
// so round 1 reduces to x1 = rotl(x1,13) ^ x0.
// Injections after rounds 4/8/12/16/20: (x0+=A_i, x1+=B_i).
struct Keys {
  uint32_t k1, k01;
  uint32_t A1, B1, A2, B2, A3, B3, A4, B4, A5, B5;
};

__device__ __forceinline__ uint32_t rotl(uint32_t v, int n) {
  return __builtin_rotateleft32(v, n);  // v_alignbit_b32
}

// grid = (M/8/256, 4) = (1176, 4); each thread owns 8 consecutive spatial
// sites and loops 16 timesteps (blockIdx.y picks the t-segment).
// 8 independent threefry chains per iteration for ILP.
__global__ __launch_bounds__(256) void spike_encode(const float* __restrict__ x,
                                                    float* __restrict__ out,
                                                    Keys K) {
  const uint32_t m8 = (blockIdx.x * 256u + threadIdx.x) * 8u;

  const float4 xa = *reinterpret_cast<const float4*>(x + m8);
  const float4 xb = *reinterpret_cast<const float4*>(x + m8 + 4u);
  // (t - x*64 >= 0) <=> (t >= x*64); x*64 exact (pow2), subtraction of nearby
  // fp32 is exact (Sterbenz) so the compare is bit-equivalent to the ref.
  float d[8] = {xa.x * 64.0f, xa.y * 64.0f, xa.z * 64.0f, xa.w * 64.0f,
                xb.x * 64.0f, xb.y * 64.0f, xb.z * 64.0f, xb.w * 64.0f};

  const uint32_t t_begin = blockIdx.y * 16u;
  const uint32_t t_end   = t_begin + 16u;

  for (uint32_t t = t_begin; t < t_end; ++t) {
    const float tf = (float)t;
    const uint32_t j = t * M + m8;

    uint32_t x0[8], x1[8];
#pragma unroll
    for (int i = 0; i < 8; ++i) {
      x1[i] = j + (K.k1 + (uint32_t)i);
      x0[i] = j + (K.k01 + (uint32_t)i);
    }

#define RND(r) \
  _Pragma("unroll") for (int i = 0; i < 8; ++i) { \
    x0[i] += x1[i]; x1[i] = rotl(x1[i], r) ^ x0[i]; \
  }
#define INJ(A, B) \
  _Pragma("unroll") for (int i = 0; i < 8; ++i) { x0[i] += K.A; x1[i] += K.B; }

    // round 1 (x0 += x1 pre-folded into init):
#pragma unroll
    for (int i = 0; i < 8; ++i) x1[i] = rotl(x1[i], 13) ^ x0[i];
    RND(15) RND(26) RND(6)   INJ(A1, B1)
    RND(17) RND(29) RND(16) RND(24) INJ(A2, B2)
    RND(13) RND(15) RND(26) RND(6)  INJ(A3, B3)
    RND(17) RND(29) RND(16) RND(24) INJ(A4, B4)
    RND(13) RND(15) RND(26) RND(6)  INJ(A5, B5)
#undef RND
#undef INJ

    float o[8];
#pragma unroll
    for (int i = 0; i < 8; ++i) {
      const uint32_t b = x0[i] ^ x1[i];
      o[i] = ((tf >= d[i]) && (b <= BITS_LE)) ? 1.0f : 0.0f;
    }

    float4 s0 = {o[0], o[1], o[2], o[3]};
    float4 s1 = {o[4], o[5], o[6], o[7]};
    *reinterpret_cast<float4*>(out + (size_t)j)      = s0;
    *reinterpret_cast<float4*>(out + (size_t)j + 4u) = s1;
  }
}

// Host-side full threefry2x32 for key derivation.
static inline void tf2x32_host(uint32_t k0, uint32_t k1, uint32_t& x0, uint32_t& x1) {
  const uint32_t ks2 = k0 ^ k1 ^ 0x1BD11BDAu;
  x0 += k0; x1 += k1;
  auto rnd = [&](int r) { x0 += x1; x1 = (x1 << r) | (x1 >> (32 - r)); x1 ^= x0; };
  rnd(13); rnd(15); rnd(26); rnd(6);  x0 += k1;  x1 += ks2 + 1u;
  rnd(17); rnd(29); rnd(16); rnd(24); x0 += ks2; x1 += k0 + 2u;
  rnd(13); rnd(15); rnd(26); rnd(6);  x0 += k0;  x1 += k1 + 3u;
  rnd(17); rnd(29); rnd(16); rnd(24); x0 += k1;  x1 += ks2 + 4u;
  rnd(13); rnd(15); rnd(26); rnd(6);  x0 += ks2; x1 += k0 + 5u;
}

extern "C" void kernel_launch(void* const* d_in, const int* in_sizes, int n_in,
                              void* d_out, int out_size, void* d_ws, size_t ws_size,
                              hipStream_t stream) {
  (void)in_sizes; (void)n_in; (void)out_size; (void)d_ws; (void)ws_size;
  const float* x = (const float*)d_in[0];
  float* out = (float*)d_out;

  // rkey = fold_in(key(0), 1) = threefry2x32(key=(0,0), counts=(0,1))
  uint32_t rk0 = 0u, rk1 = 1u;
  tf2x32_host(0u, 0u, rk0, rk1);

  const uint32_t ks2 = rk0 ^ rk1 ^ 0x1BD11BDAu;
  Keys K;
  K.k1  = rk1;
  K.k01 = rk0 + rk1;
  K.A1 = rk1;  K.B1 = ks2 + 1u;
  K.A2 = ks2;  K.B2 = rk0 + 2u;
  K.A3 = rk0;  K.B3 = rk1 + 3u;
  K.A4 = rk1;  K.B4 = ks2 + 4u;
  K.A5 = ks2;  K.B5 = rk0 + 5u;

  dim3 grid(M / 8u / 256u, 4);  // (1176, 4): 8 sites/thread × 16 t-steps
  spike_encode<<<grid, dim3(256), 0, stream>>>(x, out, K);
}

// Round 5
// 765.846 us; speedup vs baseline: 1.1172x; 1.1172x over previous
//
#include <hip/hip_runtime.h>
#include <stdint.h>

// out[t,b,c,h,w] = (t >= 64*x) * (threefry_xor_bits(rkey, j) <= 0xC00001FF)
// out shape (64,16,3,224,224) fp32; N = 154,140,672 < 2^32.
// PRNG scheme (verified bit-exact R3/R4, absmax=0): JAX partitionable
// random_bits, 32-bit: bits[j] = o0 ^ o1 of threefry2x32(rkey, (0, j)).
static constexpr uint32_t M = 16u * 3u * 224u * 224u;  // 2,408,448 per timestep

// uniform = bitcast((bits>>9)|0x3F800000)-1 <= 0.75  <=>  bits <= 0xC00001FF
static constexpr uint32_t BITS_LE = 0xC00001FFu;

// Host-precomputed threefry key schedule.
//  counts = (0, j): x0_in = rk0 (uniform), x1_in = j + rk1.
//  Round-1 fold: x0 after "x0 += x1" = j + (rk0+rk1) = j + k01.
//  Injection i folded into next round's add: x0 = x0 + x1 + ABi (v_add3),
//  x1 = rotl(x1 + Bi, r) ^ x0.  ABi = Ai + Bi.
struct Keys {
  uint32_t k1, k01;
  uint32_t AB1, B1, AB2, B2, AB3, B3, AB4, B4, A5, B5;
};

__device__ __forceinline__ uint32_t rotl(uint32_t v, int n) {
  return __builtin_rotateleft32(v, n);  // v_alignbit_b32
}

// grid = (M/8/256, 64) = (1176, 64); blockIdx.y = timestep t.
// Flat structure (NO inner t-loop — R4's loop forced store-register reuse
// stalls at VGPR=28). 8 consecutive sites/thread = 8 independent threefry
// chains for ILP; stores issue once at thread end (fire-and-forget).
__global__ __launch_bounds__(256) void spike_encode(const float* __restrict__ x,
                                                    float* __restrict__ out,
                                                    Keys K) {
  const uint32_t m8 = (blockIdx.x * 256u + threadIdx.x) * 8u;
  const uint32_t t  = blockIdx.y;
  const float tf = (float)t;
  const uint32_t j = t * M + m8;

  const float4 xa = *reinterpret_cast<const float4*>(x + m8);
  const float4 xb = *reinterpret_cast<const float4*>(x + m8 + 4u);
  // (t - 64x >= 0) <=> (t >= 64x) in IEEE fp32 here (verified R4, absmax=0).
  const float d[8] = {xa.x * 64.0f, xa.y * 64.0f, xa.z * 64.0f, xa.w * 64.0f,
                      xb.x * 64.0f, xb.y * 64.0f, xb.z * 64.0f, xb.w * 64.0f};

  uint32_t x0[8], x1[8];
#pragma unroll
  for (int i = 0; i < 8; ++i) {
    x1[i] = j + (K.k1  + (uint32_t)i);
    x0[i] = j + (K.k01 + (uint32_t)i);
  }

#define RND(r) \
  _Pragma("unroll") for (int i = 0; i < 8; ++i) { \
    x0[i] += x1[i]; x1[i] = rotl(x1[i], r) ^ x0[i]; \
  }
// Injection folded into the following round (rotation r):
//   x0 = x0 + x1 + (A+B); x1 = rotl(x1 + B, r) ^ x0
#define INJR(AB, B, r) \
  _Pragma("unroll") for (int i = 0; i < 8; ++i) { \
    x0[i] = x0[i] + x1[i] + K.AB; \
    const uint32_t x1t = x1[i] + K.B; \
    x1[i] = rotl(x1t, r) ^ x0[i]; \
  }

  // round 1 (its "x0 += x1" is pre-folded into the k01 init):
#pragma unroll
  for (int i = 0; i < 8; ++i) x1[i] = rotl(x1[i], 13) ^ x0[i];
  RND(15) RND(26) RND(6)
  INJR(AB1, B1, 17)           // inj1 + round 5
  RND(29) RND(16) RND(24)
  INJR(AB2, B2, 13)           // inj2 + round 9
  RND(15) RND(26) RND(6)
  INJR(AB3, B3, 17)           // inj3 + round 13
  RND(29) RND(16) RND(24)
  INJR(AB4, B4, 13)           // inj4 + round 17
  RND(15) RND(26) RND(6)      // rounds 18-20
#undef RND
#undef INJR

  float o[8];
#pragma unroll
  for (int i = 0; i < 8; ++i) {
    const uint32_t b = (x0[i] + K.A5) ^ (x1[i] + K.B5);  // terminal injection
    o[i] = ((tf >= d[i]) && (b <= BITS_LE)) ? 1.0f : 0.0f;
  }

  const float4 s0 = {o[0], o[1], o[2], o[3]};
  const float4 s1 = {o[4], o[5], o[6], o[7]};
  *reinterpret_cast<float4*>(out + (size_t)j)      = s0;
  *reinterpret_cast<float4*>(out + (size_t)j + 4u) = s1;
}

// Host-side full threefry2x32 for key derivation.
static inline void tf2x32_host(uint32_t k0, uint32_t k1, uint32_t& x0, uint32_t& x1) {
  const uint32_t ks2 = k0 ^ k1 ^ 0x1BD11BDAu;
  x0 += k0; x1 += k1;
  auto rnd = [&](int r) { x0 += x1; x1 = (x1 << r) | (x1 >> (32 - r)); x1 ^= x0; };
  rnd(13); rnd(15); rnd(26); rnd(6);  x0 += k1;  x1 += ks2 + 1u;
  rnd(17); rnd(29); rnd(16); rnd(24); x0 += ks2; x1 += k0 + 2u;
  rnd(13); rnd(15); rnd(26); rnd(6);  x0 += k0;  x1 += k1 + 3u;
  rnd(17); rnd(29); rnd(16); rnd(24); x0 += k1;  x1 += ks2 + 4u;
  rnd(13); rnd(15); rnd(26); rnd(6);  x0 += ks2; x1 += k0 + 5u;
}

extern "C" void kernel_launch(void* const* d_in, const int* in_sizes, int n_in,
                              void* d_out, int out_size, void* d_ws, size_t ws_size,
                              hipStream_t stream) {
  (void)in_sizes; (void)n_in; (void)out_size; (void)d_ws; (void)ws_size;
  const float* x = (const float*)d_in[0];
  float* out = (float*)d_out;

  // rkey = fold_in(key(0), 1) = threefry2x32(key=(0,0), counts=(0,1))
  uint32_t rk0 = 0u, rk1 = 1u;
  tf2x32_host(0u, 0u, rk0, rk1);

  const uint32_t ks2 = rk0 ^ rk1 ^ 0x1BD11BDAu;
  Keys K;
  K.k1  = rk1;
  K.k01 = rk0 + rk1;
  const uint32_t A1 = rk1, B1 = ks2 + 1u;
  const uint32_t A2 = ks2, B2 = rk0 + 2u;
  const uint32_t A3 = rk0, B3 = rk1 + 3u;
  const uint32_t A4 = rk1, B4 = ks2 + 4u;
  K.AB1 = A1 + B1; K.B1 = B1;
  K.AB2 = A2 + B2; K.B2 = B2;
  K.AB3 = A3 + B3; K.B3 = B3;
  K.AB4 = A4 + B4; K.B4 = B4;
  K.A5  = ks2;     K.B5 = rk0 + 5u;

  dim3 grid(M / 8u / 256u, 64);  // (1176, 64), flat: one t per thread
  spike_encode<<<grid, dim3(256), 0, stream>>>(x, out, K);
}